// Round 2
// baseline (315.612 us; speedup 1.0000x reference)
//
#include <hip/hip_runtime.h>

#define B_   128
#define I_   4608
#define O_   10
#define D_   16
#define IPB  18          // i's per block
#define NBLK 256         // 4608 = 256*18

// ---- bf16 pack/unpack (round-to-nearest-even-ish) ----
__device__ __forceinline__ unsigned int pack_bf16_pair(float hi, float lo) {
    unsigned int uh = __float_as_uint(hi);
    unsigned int ul = __float_as_uint(lo);
    uh += 0x7fffu + ((uh >> 16) & 1u);
    ul += 0x7fffu + ((ul >> 16) & 1u);
    return (uh & 0xffff0000u) | (ul >> 16);
}
__device__ __forceinline__ float unpack_lo(unsigned int p) { return __uint_as_float(p << 16); }
__device__ __forceinline__ float unpack_hi(unsigned int p) { return __uint_as_float(p & 0xffff0000u); }

// ---------------------------------------------------------------------------
// Pass kernel. 320 threads = o(10 lanes-groups) x b-quad(32).
// Thread owns: 1 o, 4 b's, all 16 d. W streamed from global (no LDS tile).
// MODE 0: acc[b][d] += x_hat                  (uniform c folded in reduce)
// MODE 1: bd[b]=sum_d v*xh (thread-local); softmax over o via tiny LDS
//         exchange; acc[b][d] += c*xh.
// ---------------------------------------------------------------------------
template<int MODE>
__global__ __launch_bounds__(320, 2)
void pass_kernel(const float* __restrict__ x,     // [128][4608][8]
                 const float* __restrict__ w,     // [10][4608][16][8]
                 const float* __restrict__ v,     // [128][10][16]
                 float* __restrict__ parts)       // [NBLK][128][10][16]
{
    __shared__ float el[O_][B_];      // exp(logit) per (o, b)
    __shared__ float invSl[B_];       // 1/sum_o exp

    const int tid = threadIdx.x;
    const int o   = tid >> 5;         // 0..9
    const int b4  = tid & 31;         // b-quad index
    const int b0  = b4 * 4;
    const int i0  = blockIdx.x * IPB;

    float acc[4][16];
#pragma unroll
    for (int bb = 0; bb < 4; ++bb)
#pragma unroll
        for (int d = 0; d < 16; ++d) acc[bb][d] = 0.f;

    unsigned int vvp[4][8];           // v[b][o][d] bf16-packed along d pairs
    if (MODE == 1) {
#pragma unroll
        for (int bb = 0; bb < 4; ++bb) {
            const float* vp = v + ((long)(b0 + bb) * O_ + o) * D_;
#pragma unroll
            for (int dp = 0; dp < 8; ++dp)
                vvp[bb][dp] = pack_bf16_pair(vp[2 * dp + 1], vp[2 * dp]);
        }
    }

    const float* wbase = w + ((long)(o * I_ + i0)) * 128;   // this o's W slice
    const float* xb0 = x + ((long)(b0 + 0) * I_ + i0) * 8;
    const float* xb1 = x + ((long)(b0 + 1) * I_ + i0) * 8;
    const float* xb2 = x + ((long)(b0 + 2) * I_ + i0) * 8;
    const float* xb3 = x + ((long)(b0 + 3) * I_ + i0) * 8;

#pragma unroll 1
    for (int ii = 0; ii < IPB; ++ii) {
        // ---- x[b][i][0..7] ----
        float xk[4][8];
        {
            const float* xp[4] = {xb0 + ii * 8, xb1 + ii * 8, xb2 + ii * 8, xb3 + ii * 8};
#pragma unroll
            for (int bb = 0; bb < 4; ++bb) {
                float4 a = *reinterpret_cast<const float4*>(xp[bb]);
                float4 b = *reinterpret_cast<const float4*>(xp[bb] + 4);
                xk[bb][0] = a.x; xk[bb][1] = a.y; xk[bb][2] = a.z; xk[bb][3] = a.w;
                xk[bb][4] = b.x; xk[bb][5] = b.y; xk[bb][6] = b.z; xk[bb][7] = b.w;
            }
        }

        const float* wp = wbase + ii * 128;   // [16 d][8 k] contiguous
        float xh[4][16];
        float bd[4] = {0.f, 0.f, 0.f, 0.f};

#pragma unroll
        for (int dq = 0; dq < 4; ++dq) {
            // 8 W loads for this d-quad (base + small imm offsets)
            float4 wv[8];
#pragma unroll
            for (int dd = 0; dd < 4; ++dd) {
                wv[dd * 2 + 0] = *reinterpret_cast<const float4*>(wp + (dq * 4 + dd) * 8);
                wv[dd * 2 + 1] = *reinterpret_cast<const float4*>(wp + (dq * 4 + dd) * 8 + 4);
            }
#pragma unroll
            for (int dd = 0; dd < 4; ++dd) {
                const int d = dq * 4 + dd;
                const float4 wa = wv[dd * 2 + 0];
                const float4 wb = wv[dd * 2 + 1];
#pragma unroll
                for (int bb = 0; bb < 4; ++bb) {
                    float h;
                    h = wa.x * xk[bb][0];
                    h = fmaf(wa.y, xk[bb][1], h);
                    h = fmaf(wa.z, xk[bb][2], h);
                    h = fmaf(wa.w, xk[bb][3], h);
                    h = fmaf(wb.x, xk[bb][4], h);
                    h = fmaf(wb.y, xk[bb][5], h);
                    h = fmaf(wb.z, xk[bb][6], h);
                    h = fmaf(wb.w, xk[bb][7], h);
                    if (MODE == 0) {
                        acc[bb][d] += h;
                    } else {
                        xh[bb][d] = h;
                        const unsigned int p = vvp[bb][d >> 1];
                        const float vvf = (d & 1) ? unpack_hi(p) : unpack_lo(p);
                        bd[bb] = fmaf(vvf, h, bd[bb]);
                    }
                }
            }
        }

        if (MODE == 1) {
            // logits are bounded (|bd| < ~4) -> skip max-subtraction
            float e0 = __expf(bd[0]), e1 = __expf(bd[1]);
            float e2 = __expf(bd[2]), e3 = __expf(bd[3]);
            *reinterpret_cast<float4*>(&el[o][b0]) = make_float4(e0, e1, e2, e3);
            __syncthreads();
            if (tid < B_) {
                float s = 0.f;
#pragma unroll
                for (int oo = 0; oo < O_; ++oo) s += el[oo][tid];
                invSl[tid] = 1.f / s;
            }
            __syncthreads();
            const float4 iv = *reinterpret_cast<const float4*>(&invSl[b0]);
            const float cs[4] = {e0 * iv.x, e1 * iv.y, e2 * iv.z, e3 * iv.w};
#pragma unroll
            for (int bb = 0; bb < 4; ++bb)
#pragma unroll
                for (int d = 0; d < 16; ++d)
                    acc[bb][d] = fmaf(cs[bb], xh[bb][d], acc[bb][d]);
        }
    }

    // ---- block-partial write: parts[blk][b][o][d] ----
    float* p = parts + (long)blockIdx.x * (B_ * O_ * D_) + o * D_;
#pragma unroll
    for (int bb = 0; bb < 4; ++bb) {
#pragma unroll
        for (int dq = 0; dq < 4; ++dq) {
            float4 t = make_float4(acc[bb][dq * 4 + 0], acc[bb][dq * 4 + 1],
                                   acc[bb][dq * 4 + 2], acc[bb][dq * 4 + 3]);
            *reinterpret_cast<float4*>(p + (long)(b0 + bb) * (O_ * D_) + dq * 4) = t;
        }
    }
}

// ---------------------------------------------------------------------------
// Reduce partials -> s[b,o,d]; squash over d; update v_buf and output accum.
// ---------------------------------------------------------------------------
__global__ __launch_bounds__(256)
void reduce_squash(const float* __restrict__ parts, float* __restrict__ v_buf,
                   float* __restrict__ out, float kscale, float pre, int mode)
{
    const int tid = threadIdx.x;
    const int g   = blockIdx.x * 16 + (tid >> 4);   // (b*O + o), 0..1279
    const int d   = tid & 15;
    const int idx = g * D_ + d;

    float s = 0.f;
    for (int p = 0; p < NBLK; ++p)
        s += parts[(long)p * (B_ * O_ * D_) + idx];
    s *= pre;

    float n2 = s * s;
    n2 += __shfl_xor(n2, 1);
    n2 += __shfl_xor(n2, 2);
    n2 += __shfl_xor(n2, 4);
    n2 += __shfl_xor(n2, 8);
    const float n     = sqrtf(n2);
    const float scale = n2 / ((1.f + n2) * (n + 1e-8f));
    const float o_    = scale * s;

    if (mode == 0)      { v_buf[idx] = o_;  out[idx]  = kscale * o_; }
    else if (mode == 1) { v_buf[idx] += o_; out[idx] += kscale * o_; }
    else                {                   out[idx] += kscale * o_; }
}

// ---------------------------------------------------------------------------
extern "C" void kernel_launch(void* const* d_in, const int* in_sizes, int n_in,
                              void* d_out, int out_size, void* d_ws, size_t ws_size,
                              hipStream_t stream)
{
    const float* x = (const float*)d_in[0];   // [128,4608,8]
    const float* w = (const float*)d_in[1];   // [10,4608,16,8]
    float* out   = (float*)d_out;             // [128,10,16]
    float* parts = (float*)d_ws;              // NBLK * 20480 floats = 21 MB
    float* v_buf = parts + (long)NBLK * (B_ * O_ * D_);

    // iter 0: c = 1/10 uniform (folded via pre=0.1)
    pass_kernel<0><<<NBLK, 320, 0, stream>>>(x, w, v_buf, parts);
    reduce_squash<<<80, 256, 0, stream>>>(parts, v_buf, out, 0.3f, 0.1f, 0);

    // iter 1: b1 = <out0, xh>
    pass_kernel<1><<<NBLK, 320, 0, stream>>>(x, w, v_buf, parts);
    reduce_squash<<<80, 256, 0, stream>>>(parts, v_buf, out, 0.3f, 1.0f, 1);

    // iter 2: b2 = <out0 + out1, xh>
    pass_kernel<1><<<NBLK, 320, 0, stream>>>(x, w, v_buf, parts);
    reduce_squash<<<80, 256, 0, stream>>>(parts, v_buf, out, 0.4f, 1.0f, 2);
}

// Round 4
// 111.359 us; speedup vs baseline: 2.8342x; 2.8342x over previous
//
#include <hip/hip_runtime.h>

#define B_   128
#define I_   4608
#define O_   10
#define D_   16
#define IPB  18
#define NBLK 256
#define NCH  9          // 9 chunks of 2 i's = 18 i per block
#define RST  168        // image row stride (halves), 336 B
#define QST  40         // group stride (halves), 80 B
#define IMG_H (16*RST)  // 2688 halves per image

typedef _Float16 f16x4 __attribute__((ext_vector_type(4)));
typedef _Float16 f16x8 __attribute__((ext_vector_type(8)));
typedef float    f32x4 __attribute__((ext_vector_type(4)));
typedef __fp16   pk16x2 __attribute__((ext_vector_type(2)));
typedef unsigned int uint2v __attribute__((ext_vector_type(2)));

__device__ __forceinline__ f16x4 pack4(float a, float b, float c, float d) {
    union { f16x4 v; pk16x2 p[2]; } u;
    u.p[0] = __builtin_amdgcn_cvt_pkrtz(a, b);
    u.p[1] = __builtin_amdgcn_cvt_pkrtz(c, d);
    return u.v;
}

// ---------------------------------------------------------------------------
// MFMA routing pass. Block = 512 thr = 8 waves; wave w owns b-tile [16w,16w+16).
// Per 2-i chunk, per o:  u^T[ik,b] = Wt x v   (16x16x16 f16, K=d=16)
//   bd[b,i] = sum_k u*x (in-lane + permlane32_swap), softmax over o in-lane,
//   S[d,b] += P x (c*x)  (16x16x16 f16, K=ik=16), S accumulated in C-frags.
// Row/K permutation sigma(m) = (m>>2&1)*8 + (m>>3)*4 + (m&3) baked into both
// LDS images so lane-group g works on i_loc = g&1, k-quad = g>>1 throughout.
// MODE 0: c uniform (folded as pre=0.1 in reduce): skip u/bd/softmax.
// ---------------------------------------------------------------------------
template<int MODE>
__global__ __launch_bounds__(512, 2)
void pass_kernel(const float* __restrict__ x,     // [128][4608][8]
                 const float* __restrict__ w,     // [10][4608][16][8]
                 const float* __restrict__ v,     // [128][10][16]
                 float* __restrict__ parts)       // [NBLK][128][10][16]
{
    __shared__ _Float16 lds[2][2][IMG_H];   // [buf][0=Wt2 u-img, 1=P2 apply-img]

    const int tid  = threadIdx.x;
    const int lane = tid & 63;
    const int wv   = tid >> 6;
    const int bl   = lane & 15;
    const int g    = lane >> 4;
    const int b    = wv * 16 + bl;
    const int i0   = blockIdx.x * IPB;

    // ---- staging slot decode: 640 b64-slots per image, 2 rounds ----
    int  s_wa[2]; long s_gP[2]; long s_gW[2]; bool s_act[2];
#pragma unroll
    for (int rd = 0; rd < 2; ++rd) {
        const int s = tid + rd * 512;
        s_act[rd] = (s < 640);
        const int ss = s_act[rd] ? s : 0;
        const int o = ss % 10;
        const int t = ss / 10;
        const int q = t & 3, r = t >> 2;
        s_wa[rd] = r * RST + q * QST + (o >> 1) * 8 + (o & 1) * 4;
        // P2 slot (d=r, g=q): dwordx4 = W[o][i0c+(q&1)][r][(q>>1)*4 .. +3]
        s_gP[rd] = (long)o * I_ * 128 + (long)(q & 1) * 128 + r * 8 + (q >> 1) * 4;
        // Wt2 slot (m=r, g=q): 4 strided dwords W[o][i0c+((r>>2)&1)][q*4+jj][(r>>3)*4+(r&3)]
        s_gW[rd] = (long)o * I_ * 128 + (long)((r >> 2) & 1) * 128 + q * 32
                 + (r >> 3) * 4 + (r & 3);
    }

    float4 pl[2];
    float  wl[2][4];

    auto load_stage = [&](int ic) {
        const long ioff = (long)ic * 128;
#pragma unroll
        for (int rd = 0; rd < 2; ++rd) if (s_act[rd]) {
            pl[rd] = *(const float4*)(w + s_gP[rd] + ioff);
            if (MODE == 1) {
                const float* wp = w + s_gW[rd] + ioff;
                wl[rd][0] = wp[0];  wl[rd][1] = wp[8];
                wl[rd][2] = wp[16]; wl[rd][3] = wp[24];
            }
        }
    };
    auto write_stage = [&](int buf) {
        _Float16* wt2 = &lds[buf][0][0];
        _Float16* p2  = &lds[buf][1][0];
#pragma unroll
        for (int rd = 0; rd < 2; ++rd) if (s_act[rd]) {
            *(f16x4*)(p2 + s_wa[rd]) = pack4(pl[rd].x, pl[rd].y, pl[rd].z, pl[rd].w);
            if (MODE == 1)
                *(f16x4*)(wt2 + s_wa[rd]) = pack4(wl[rd][0], wl[rd][1], wl[rd][2], wl[rd][3]);
        }
    };

    // ---- v B-fragments (static per kernel): B[k=d][n=b], d = g*4+j ----
    f16x4 vf[O_];
    if (MODE == 1) {
#pragma unroll
        for (int o = 0; o < O_; ++o) {
            const float4 vv = *(const float4*)(v + ((long)b * O_ + o) * D_ + g * 4);
            vf[o] = pack4(vv.x, vv.y, vv.z, vv.w);
        }
    }

    f32x4 S[O_];
#pragma unroll
    for (int o = 0; o < O_; ++o) S[o] = (f32x4)(0.f);

    const int rdo  = bl * RST + g * QST;   // lane frag base (halves)
    const int iloc = g & 1, kq = g >> 1;

    load_stage(i0);
    write_stage(0);

    for (int c = 0; c < NCH; ++c) {
        if (c + 1 < NCH) load_stage(i0 + (c + 1) * 2);
        __syncthreads();
        const _Float16* wt2 = &lds[c & 1][0][0];
        const _Float16* p2  = &lds[c & 1][1][0];

        const float4 xq = *(const float4*)(x + ((long)b * I_ + i0 + c * 2 + iloc) * 8 + kq * 4);

        float cs[O_];
        if (MODE == 1) {
            // logits: u = Wt2-frag x v, bd = sum_k u*x
#pragma unroll
            for (int p = 0; p < 5; ++p) {
                const f16x8 af = *(const f16x8*)(wt2 + rdo + p * 8);
                f16x4 ae, ao;
                ae[0]=af[0]; ae[1]=af[1]; ae[2]=af[2]; ae[3]=af[3];
                ao[0]=af[4]; ao[1]=af[5]; ao[2]=af[6]; ao[3]=af[7];
                f32x4 u0 = __builtin_amdgcn_mfma_f32_16x16x16f16(ae, vf[2*p],   (f32x4)(0.f), 0, 0, 0);
                f32x4 u1 = __builtin_amdgcn_mfma_f32_16x16x16f16(ao, vf[2*p+1], (f32x4)(0.f), 0, 0, 0);
                float d0 = u0[0] * xq.x; d0 = fmaf(u0[1], xq.y, d0);
                d0 = fmaf(u0[2], xq.z, d0); d0 = fmaf(u0[3], xq.w, d0);
                float d1 = u1[0] * xq.x; d1 = fmaf(u1[1], xq.y, d1);
                d1 = fmaf(u1[2], xq.z, d1); d1 = fmaf(u1[3], xq.w, d1);
                cs[2*p] = d0; cs[2*p+1] = d1;
            }
            float ssum = 0.f;
#pragma unroll
            for (int o = 0; o < O_; ++o) {
                const unsigned int t = __float_as_uint(cs[o]);
                const uint2v sw = __builtin_amdgcn_permlane32_swap(t, t, false, false);
                // lane j: sw[0]+sw[1] = t[j] + t[j^32]  (both k-quads summed)
                const float e = __expf(__uint_as_float(sw[0]) + __uint_as_float(sw[1]));
                cs[o] = e; ssum += e;
            }
            const float inv = 1.f / ssum;
#pragma unroll
            for (int o = 0; o < O_; ++o) cs[o] *= inv;
        }

        f16x4 y0;
        if (MODE == 0) y0 = pack4(xq.x, xq.y, xq.z, xq.w);

        // apply: S[d,b] += P2-frag x y
#pragma unroll
        for (int p = 0; p < 5; ++p) {
            const f16x8 pf = *(const f16x8*)(p2 + rdo + p * 8);
            f16x4 pe, po;
            pe[0]=pf[0]; pe[1]=pf[1]; pe[2]=pf[2]; pe[3]=pf[3];
            po[0]=pf[4]; po[1]=pf[5]; po[2]=pf[6]; po[3]=pf[7];
            f16x4 ye, yo;
            if (MODE == 0) { ye = y0; yo = y0; }
            else {
                ye = pack4(cs[2*p]*xq.x,   cs[2*p]*xq.y,   cs[2*p]*xq.z,   cs[2*p]*xq.w);
                yo = pack4(cs[2*p+1]*xq.x, cs[2*p+1]*xq.y, cs[2*p+1]*xq.z, cs[2*p+1]*xq.w);
            }
            S[2*p]   = __builtin_amdgcn_mfma_f32_16x16x16f16(pe, ye, S[2*p],   0, 0, 0);
            S[2*p+1] = __builtin_amdgcn_mfma_f32_16x16x16f16(po, yo, S[2*p+1], 0, 0, 0);
        }

        if (c + 1 < NCH) write_stage((c + 1) & 1);
    }

    // C-frag: col = b = lane&15, row = d = g*4+reg -> parts[blk][b][o][d]
    float* pp = parts + ((long)blockIdx.x * B_ + b) * (O_ * D_) + g * 4;
#pragma unroll
    for (int o = 0; o < O_; ++o)
        *(f32x4*)(pp + o * D_) = S[o];
}

// ---------------------------------------------------------------------------
// Reduce partials -> s[b,o,d]; squash over d; update v_buf and output accum.
// ---------------------------------------------------------------------------
__global__ __launch_bounds__(256)
void reduce_squash(const float* __restrict__ parts, float* __restrict__ v_buf,
                   float* __restrict__ out, float kscale, float pre, int mode)
{
    const int tid = threadIdx.x;
    const int gg  = blockIdx.x * 16 + (tid >> 4);   // (b*O + o), 0..1279
    const int d   = tid & 15;
    const int idx = gg * D_ + d;

    float s = 0.f;
    for (int p = 0; p < NBLK; ++p)
        s += parts[(long)p * (B_ * O_ * D_) + idx];
    s *= pre;

    float n2 = s * s;
    n2 += __shfl_xor(n2, 1);
    n2 += __shfl_xor(n2, 2);
    n2 += __shfl_xor(n2, 4);
    n2 += __shfl_xor(n2, 8);
    const float n     = sqrtf(n2);
    const float scale = n2 / ((1.f + n2) * (n + 1e-8f));
    const float o_    = scale * s;

    if (mode == 0)      { v_buf[idx] = o_;  out[idx]  = kscale * o_; }
    else if (mode == 1) { v_buf[idx] += o_; out[idx] += kscale * o_; }
    else                {                   out[idx] += kscale * o_; }
}

// ---------------------------------------------------------------------------
extern "C" void kernel_launch(void* const* d_in, const int* in_sizes, int n_in,
                              void* d_out, int out_size, void* d_ws, size_t ws_size,
                              hipStream_t stream)
{
    const float* x = (const float*)d_in[0];   // [128,4608,8]
    const float* w = (const float*)d_in[1];   // [10,4608,16,8]
    float* out   = (float*)d_out;             // [128,10,16]
    float* parts = (float*)d_ws;              // NBLK * 20480 floats = 21 MB
    float* v_buf = parts + (long)NBLK * (B_ * O_ * D_);

    // iter 0: c = 1/10 uniform (folded via pre=0.1)
    pass_kernel<0><<<NBLK, 512, 0, stream>>>(x, w, v_buf, parts);
    reduce_squash<<<80, 256, 0, stream>>>(parts, v_buf, out, 0.3f, 0.1f, 0);

    // iter 1: b1 = <out0, xh>
    pass_kernel<1><<<NBLK, 512, 0, stream>>>(x, w, v_buf, parts);
    reduce_squash<<<80, 256, 0, stream>>>(parts, v_buf, out, 0.3f, 1.0f, 1);

    // iter 2: b2 = <out0 + out1, xh>
    pass_kernel<1><<<NBLK, 512, 0, stream>>>(x, w, v_buf, parts);
    reduce_squash<<<80, 256, 0, stream>>>(parts, v_buf, out, 0.4f, 1.0f, 2);
}

// Round 5
// 97.343 us; speedup vs baseline: 3.2423x; 1.1440x over previous
//
#include <hip/hip_runtime.h>

#define B_    128
#define I_    4608
#define O_    10
#define D_    16
#define IPB   18
#define NBLK  256
#define NCH   9           // chunks of 2 i's per block
#define NCHUNKS 2304      // I_/2
#define RST   168         // image row stride (halves)
#define QST   40          // group stride (halves)
#define IMG_H 2688        // halves per image (16*RST)
#define CHH   5376        // halves per prepped chunk (2 images)

typedef _Float16 f16x4 __attribute__((ext_vector_type(4)));
typedef _Float16 f16x8 __attribute__((ext_vector_type(8)));
typedef float    f32x4 __attribute__((ext_vector_type(4)));
typedef __fp16   pk16x2 __attribute__((ext_vector_type(2)));
typedef unsigned int uint2v __attribute__((ext_vector_type(2)));

__device__ __forceinline__ f16x4 pack4(float a, float b, float c, float d) {
    union { f16x4 v; pk16x2 p[2]; } u;
    u.p[0] = __builtin_amdgcn_cvt_pkrtz(a, b);
    u.p[1] = __builtin_amdgcn_cvt_pkrtz(c, d);
    return u.v;
}

// ---------------------------------------------------------------------------
// Prep: reformat W [10][4608][16][8] fp32 into per-chunk f16 LDS images,
// written verbatim (padded rows) so pass staging is a contiguous copy.
// Chunk c (= i-pair): img0 = Wt2 (u-GEMM A: row m=(ik sigma), col d),
//                     img1 = P2  (apply A: row d, col (ik sigma)).
// sigma(m) = (i=(m>>2)&1, k=(m>>3)*4+(m&3)); o-pairs packed per 8 halves.
// ---------------------------------------------------------------------------
__global__ __launch_bounds__(256)
void prep_kernel(const float* __restrict__ w, _Float16* __restrict__ pw)
{
    __shared__ float wch[2560];           // [o][iloc*128 + d*8 + k]
    const int c = blockIdx.x, t = threadIdx.x;
#pragma unroll
    for (int o = 0; o < O_; ++o)
        wch[o * 256 + t] = w[(long)o * I_ * 128 + (long)c * 256 + t];
    __syncthreads();

    _Float16* dst = pw + (long)c * CHH;
#pragma unroll
    for (int kk = 0; kk < 5; ++kk) {
        const int sidx = t + kk * 256;    // 0..1279
        const int img = sidx / 640;
        const int v   = sidx % 640;
        const int o   = v % 10;
        const int rq  = v / 10;
        const int r   = rq >> 2, q = rq & 3;
        f16x4 val;
        if (img == 1) {  // P2: row r=d, group q=(iloc,kq): 4 consecutive k's
            const float4 g = *(const float4*)&wch[o * 256 + (q & 1) * 128 + r * 8 + (q >> 1) * 4];
            val = pack4(g.x, g.y, g.z, g.w);
        } else {         // Wt2: row r=(ik sigma), group q: d = q*4+j
            const int bofs = o * 256 + ((r >> 2) & 1) * 128 + (r >> 3) * 4 + (r & 3);
            val = pack4(wch[bofs + (q * 4 + 0) * 8], wch[bofs + (q * 4 + 1) * 8],
                        wch[bofs + (q * 4 + 2) * 8], wch[bofs + (q * 4 + 3) * 8]);
        }
        *(f16x4*)(dst + img * IMG_H + r * RST + q * QST + o * 4) = val;
    }
}

// ---------------------------------------------------------------------------
// MFMA routing pass. 512 thr = 8 waves; wave w owns b-tile [16w,16w+16).
// Staging = contiguous 16B/lane copy of the prepped chunk (T14 split:
// issue loads after barrier, ds_write after compute). One barrier per chunk.
// MODE 0: uniform c (folded as pre=0.1 in reduce): only P2 image staged.
// ---------------------------------------------------------------------------
template<int MODE>
__global__ __launch_bounds__(512, 2)
void pass_kernel(const float* __restrict__ x,      // [128][4608][8]
                 const _Float16* __restrict__ pw,  // prepped images
                 const float* __restrict__ v,      // [128][10][16]
                 float* __restrict__ parts)        // [NBLK][128][10][16]
{
    __shared__ _Float16 lds[2][CHH];

    const int tid  = threadIdx.x;
    const int lane = tid & 63;
    const int wv   = tid >> 6;
    const int bl   = lane & 15;
    const int g    = lane >> 4;
    const int b    = wv * 16 + bl;
    const int c0   = blockIdx.x * NCH;

    const int  NS  = (MODE == 1) ? 672 : 336;   // 16B slots per chunk
    const int  u0  = tid;
    const int  u1  = tid + 512;
    const bool a0  = u0 < NS;
    const bool a1  = (MODE == 1) && (u1 < NS);
    const long srcoff = (MODE == 1) ? 0 : IMG_H;   // MODE0: only img1

    f16x4 vf[O_];
    if (MODE == 1) {
#pragma unroll
        for (int o = 0; o < O_; ++o) {
            const float4 vv = *(const float4*)(v + ((long)b * O_ + o) * D_ + g * 4);
            vf[o] = pack4(vv.x, vv.y, vv.z, vv.w);
        }
    }

    f32x4 S[O_];
#pragma unroll
    for (int o = 0; o < O_; ++o) S[o] = (f32x4)(0.f);

    const int rdo  = bl * RST + g * QST;
    const int iloc = g & 1, kq = g >> 1;

    float4 st0, st1;
    auto issue = [&](int c) {
        const _Float16* pc = pw + (long)(c0 + c) * CHH + srcoff;
        if (a0) st0 = *(const float4*)(pc + (long)u0 * 8);
        if (a1) st1 = *(const float4*)(pc + (long)u1 * 8);
    };
    auto wr = [&](int buf) {
        if (a0) *(float4*)&lds[buf][(long)u0 * 8] = st0;
        if (a1) *(float4*)&lds[buf][(long)u1 * 8] = st1;
    };
    auto xaddr = [&](int c) {
        return x + ((long)b * I_ + (long)(blockIdx.x * IPB + 2 * c + iloc)) * 8 + kq * 4;
    };

    issue(0);
    float4 xq_n = *(const float4*)xaddr(0);
    wr(0);

    for (int c = 0; c < NCH; ++c) {
        __syncthreads();
        const float4 xq = xq_n;
        if (c + 1 < NCH) { issue(c + 1); xq_n = *(const float4*)xaddr(c + 1); }

        const _Float16* wt2 = &lds[c & 1][0];
        const _Float16* p2  = &lds[c & 1][(MODE == 1) ? IMG_H : 0];

        float cs[O_];
        if (MODE == 1) {
            // logits: u = Wt2-frag x v ; bd = sum_k u*x ; softmax over o
#pragma unroll
            for (int p = 0; p < 5; ++p) {
                const f16x8 af = *(const f16x8*)(wt2 + rdo + p * 8);
                f16x4 ae, ao;
                ae[0]=af[0]; ae[1]=af[1]; ae[2]=af[2]; ae[3]=af[3];
                ao[0]=af[4]; ao[1]=af[5]; ao[2]=af[6]; ao[3]=af[7];
                f32x4 ua = __builtin_amdgcn_mfma_f32_16x16x16f16(ae, vf[2*p],   (f32x4)(0.f), 0, 0, 0);
                f32x4 ub = __builtin_amdgcn_mfma_f32_16x16x16f16(ao, vf[2*p+1], (f32x4)(0.f), 0, 0, 0);
                float d0 = ua[0] * xq.x; d0 = fmaf(ua[1], xq.y, d0);
                d0 = fmaf(ua[2], xq.z, d0); d0 = fmaf(ua[3], xq.w, d0);
                float d1 = ub[0] * xq.x; d1 = fmaf(ub[1], xq.y, d1);
                d1 = fmaf(ub[2], xq.z, d1); d1 = fmaf(ub[3], xq.w, d1);
                cs[2*p] = d0; cs[2*p+1] = d1;
            }
            float ssum = 0.f;
#pragma unroll
            for (int o = 0; o < O_; ++o) {
                const unsigned int t = __float_as_uint(cs[o]);
                const uint2v sw = __builtin_amdgcn_permlane32_swap(t, t, false, false);
                const float e = __expf(__uint_as_float(sw[0]) + __uint_as_float(sw[1]));
                cs[o] = e; ssum += e;
            }
            const float inv = 1.f / ssum;
#pragma unroll
            for (int o = 0; o < O_; ++o) cs[o] *= inv;
        }

        f16x4 y0;
        if (MODE == 0) y0 = pack4(xq.x, xq.y, xq.z, xq.w);

#pragma unroll
        for (int p = 0; p < 5; ++p) {
            const f16x8 pf = *(const f16x8*)(p2 + rdo + p * 8);
            f16x4 pe, po;
            pe[0]=pf[0]; pe[1]=pf[1]; pe[2]=pf[2]; pe[3]=pf[3];
            po[0]=pf[4]; po[1]=pf[5]; po[2]=pf[6]; po[3]=pf[7];
            f16x4 ye, yo;
            if (MODE == 0) { ye = y0; yo = y0; }
            else {
                ye = pack4(cs[2*p]*xq.x,   cs[2*p]*xq.y,   cs[2*p]*xq.z,   cs[2*p]*xq.w);
                yo = pack4(cs[2*p+1]*xq.x, cs[2*p+1]*xq.y, cs[2*p+1]*xq.z, cs[2*p+1]*xq.w);
            }
            S[2*p]   = __builtin_amdgcn_mfma_f32_16x16x16f16(pe, ye, S[2*p],   0, 0, 0);
            S[2*p+1] = __builtin_amdgcn_mfma_f32_16x16x16f16(po, yo, S[2*p+1], 0, 0, 0);
        }

        if (c + 1 < NCH) wr((c + 1) & 1);
    }

    // C-frag: col = b = lane&15, row = d = g*4+reg -> parts[blk][b][o][d]
    float* pp = parts + ((long)blockIdx.x * B_ + b) * (O_ * D_) + g * 4;
#pragma unroll
    for (int o = 0; o < O_; ++o)
        *(f32x4*)(pp + o * D_) = S[o];
}

// ---------------------------------------------------------------------------
// Reduce partials -> s[b,o,d]; squash over d; update v_buf and output accum.
// Grid 1280 (one block per (b,o)); 16-way split of the 256-partial sum.
// ---------------------------------------------------------------------------
__global__ __launch_bounds__(256)
void reduce_squash(const float* __restrict__ parts, float* __restrict__ v_buf,
                   float* __restrict__ out, float kscale, float pre, int mode)
{
    __shared__ float red[4][16];
    const int tid  = threadIdx.x;
    const int lane = tid & 63;
    const int wv   = tid >> 6;
    const int g2   = blockIdx.x;        // (b*O + o)
    const int pg   = tid >> 4;          // 0..15
    const int d    = tid & 15;

    float s = 0.f;
#pragma unroll
    for (int k = 0; k < 16; ++k)
        s += parts[(long)(pg * 16 + k) * (B_ * O_ * D_) + g2 * D_ + d];

    s += __shfl_xor(s, 16);
    s += __shfl_xor(s, 32);
    if (lane < 16) red[wv][lane] = s;
    __syncthreads();

    if (tid < 16) {
        float tot = (red[0][tid] + red[1][tid]) + (red[2][tid] + red[3][tid]);
        tot *= pre;
        float n2 = tot * tot;
        n2 += __shfl_xor(n2, 1);
        n2 += __shfl_xor(n2, 2);
        n2 += __shfl_xor(n2, 4);
        n2 += __shfl_xor(n2, 8);
        const float n     = sqrtf(n2);
        const float scale = n2 / ((1.f + n2) * (n + 1e-8f));
        const float o_    = scale * tot;
        const int idx = g2 * D_ + tid;
        if (mode == 0)      { v_buf[idx] = o_;  out[idx]  = kscale * o_; }
        else if (mode == 1) { v_buf[idx] += o_; out[idx] += kscale * o_; }
        else                {                   out[idx] += kscale * o_; }
    }
}

// ---------------------------------------------------------------------------
extern "C" void kernel_launch(void* const* d_in, const int* in_sizes, int n_in,
                              void* d_out, int out_size, void* d_ws, size_t ws_size,
                              hipStream_t stream)
{
    const float* x = (const float*)d_in[0];   // [128,4608,8]
    const float* w = (const float*)d_in[1];   // [10,4608,16,8]
    float* out   = (float*)d_out;             // [128,10,16]
    float* parts = (float*)d_ws;                          // 21.0 MB
    float* v_buf = parts + (long)NBLK * (B_ * O_ * D_);   // 80 KB
    _Float16* pw = (_Float16*)(v_buf + B_ * O_ * D_);     // 24.8 MB prepped images

    prep_kernel<<<NCHUNKS, 256, 0, stream>>>(w, pw);

    // iter 0: c = 1/10 uniform (folded via pre=0.1)
    pass_kernel<0><<<NBLK, 512, 0, stream>>>(x, pw, v_buf, parts);
    reduce_squash<<<1280, 256, 0, stream>>>(parts, v_buf, out, 0.3f, 0.1f, 0);

    // iter 1: b1 = <out0, xh>
    pass_kernel<1><<<NBLK, 512, 0, stream>>>(x, pw, v_buf, parts);
    reduce_squash<<<1280, 256, 0, stream>>>(parts, v_buf, out, 0.3f, 1.0f, 1);

    // iter 2: b2 = <out0 + out1, xh>
    pass_kernel<1><<<NBLK, 512, 0, stream>>>(x, pw, v_buf, parts);
    reduce_squash<<<1280, 256, 0, stream>>>(parts, v_buf, out, 0.4f, 1.0f, 2);
}

// Round 6
// 72.403 us; speedup vs baseline: 4.3591x; 1.3445x over previous
//
#include <hip/hip_runtime.h>

#define B_    128
#define I_    4608
#define O_    10
#define D_    16
#define NCHUNKS 2304      // I_/2
#define NIB   64          // i-blocks; 72 i = 36 chunks each
#define CPB   36          // chunks per i-block
#define CHH   5120        // halves per prepped chunk: 2 img * 5 p * 64 lane * 8
#define PSET  20480       // floats per partial set (128*10*16)

typedef _Float16 f16x2 __attribute__((ext_vector_type(2)));
typedef _Float16 f16x4 __attribute__((ext_vector_type(4)));
typedef _Float16 f16x8 __attribute__((ext_vector_type(8)));
typedef float    f32x4 __attribute__((ext_vector_type(4)));
typedef __fp16   pk16x2 __attribute__((ext_vector_type(2)));
typedef unsigned int uint2v __attribute__((ext_vector_type(2)));

__device__ __forceinline__ f16x4 pack4(float a, float b, float c, float d) {
    union { f16x4 v; pk16x2 p[2]; } u;
    u.p[0] = __builtin_amdgcn_cvt_pkrtz(a, b);
    u.p[1] = __builtin_amdgcn_cvt_pkrtz(c, d);
    return u.v;
}
__device__ __forceinline__ f16x2 splat_h2(float a) {
    union { f16x2 v; pk16x2 p; } u;
    u.p = __builtin_amdgcn_cvt_pkrtz(a, a);
    return u.v;
}

// ---------------------------------------------------------------------------
// Prep: W [10][4608][16][8] fp32 -> pre-fragmented f16 images, lane-major:
// pw[chunk][img][p][lane][8 halves]; a wave's frag load is one coalesced
// dwordx4 per (img,p). img0 = Wt (u-GEMM A: row m=ik-sigma, col d),
// img1 = P (apply A: row d, col ik-sigma). lane=(r,g): r=lane&15, g=lane>>4.
// sigma: row/col n -> (iloc=(n>>2)&1, k=(n>>3)*4+(n&3)).
// ---------------------------------------------------------------------------
__global__ __launch_bounds__(256)
void prep_kernel(const float* __restrict__ w, _Float16* __restrict__ pw)
{
    __shared__ float wch[2560];           // [o][iloc*128 + d*8 + k]
    const int c = blockIdx.x, t = threadIdx.x;
#pragma unroll
    for (int o = 0; o < O_; ++o)
        wch[o * 256 + t] = w[(long)o * (I_ * 128) + (long)c * 256 + t];
    __syncthreads();

    _Float16* dst = pw + (long)c * CHH;
#pragma unroll
    for (int kk = 0; kk < 5; ++kk) {
        const int sidx = t + kk * 256;            // 0..1279 f16x4 slots
        const int hg   = sidx & 1;
        const int lane = (sidx >> 1) & 63;
        const int pi   = sidx >> 7;               // 0..9
        const int p    = pi % 5;
        const int img  = pi / 5;
        const int r = lane & 15, g = lane >> 4;
        const int o = 2 * p + hg;
        f16x4 val;
        if (img == 1) {   // P: row r=d, cols n=g*4+j -> (iloc=g&1, k=(g>>1)*4+j)
            const float4 gg = *(const float4*)&wch[o * 256 + (g & 1) * 128 + r * 8 + (g >> 1) * 4];
            val = pack4(gg.x, gg.y, gg.z, gg.w);
        } else {          // Wt: row m=r (sigma), cols d=g*4+j
            const int bofs = o * 256 + ((r >> 2) & 1) * 128 + (r >> 3) * 4 + (r & 3);
            val = pack4(wch[bofs + (g * 4 + 0) * 8], wch[bofs + (g * 4 + 1) * 8],
                        wch[bofs + (g * 4 + 2) * 8], wch[bofs + (g * 4 + 3) * 8]);
        }
        *(f16x4*)(dst + (long)sidx * 4) = val;
    }
}

// ---------------------------------------------------------------------------
// MFMA routing pass, LDS-free main loop. Grid 256 = 64 i-blocks x 4 b-groups,
// XCD-grouped (same XCD -> same i-range, pw2 slice L2-resident, 4x reuse).
// Block = 8 waves; each wave independently processes chunks c0+wv+8t (t<5,
// last guarded), covering 2 b-tiles (32 b's). Frags loaded straight from
// global (coalesced, register-pipelined). End: 3-step LDS tree over waves.
// MODE 0: uniform c (pre=0.1 in reduce): skip u-GEMM/softmax.
// ---------------------------------------------------------------------------
template<int MODE>
__global__ __launch_bounds__(512, 2)
void pass_kernel(const float* __restrict__ x,      // [128][4608][8]
                 const _Float16* __restrict__ pw,  // prepped frag images
                 const float* __restrict__ v,      // [128][10][16]
                 float* __restrict__ parts)        // [NIB][128][10][16]
{
    __shared__ float red[4 * 5120];

    const int tid  = threadIdx.x;
    const int lane = tid & 63;
    const int wv   = tid >> 6;
    const int bl   = lane & 15;
    const int g    = lane >> 4;
    const int u    = blockIdx.x;
    const int xcd  = u & 7, s = u >> 3;
    const int ib   = xcd * 8 + (s & 7);    // same-XCD blocks share ib range
    const int bg   = s >> 3;               // 0..3
    const int c0   = ib * CPB;
    const int cend = c0 + CPB;
    const int iloc = g & 1, kq = g >> 1;
    const int b0   = bg * 32 + bl;         // tile 0 b; tile 1 = b0+16

    f16x4 vf[2][O_];
    if (MODE == 1) {
#pragma unroll
        for (int tile = 0; tile < 2; ++tile)
#pragma unroll
            for (int o = 0; o < O_; ++o) {
                const float4 vv = *(const float4*)(v + ((long)(b0 + tile * 16) * O_ + o) * D_ + g * 4);
                vf[tile][o] = pack4(vv.x, vv.y, vv.z, vv.w);
            }
    }

    f32x4 S[2][O_];
#pragma unroll
    for (int tile = 0; tile < 2; ++tile)
#pragma unroll
        for (int o = 0; o < O_; ++o) S[tile][o] = (f32x4)(0.f);

    const long lofs = (long)lane * 8;
    auto fragp = [&](int c, int img, int p) {
        return (const f16x8*)(pw + (long)c * CHH + img * 2560 + p * 512 + lofs);
    };
    auto xp = [&](int c, int tile) {
        return (const float4*)(x + ((long)(b0 + tile * 16) * I_ + 2 * c + iloc) * 8 + kq * 4);
    };

    int c = c0 + wv;
    f16x8 f0[5], f1[5];
    float4 xqC[2], xqN[2];
    if (MODE == 1) {
#pragma unroll
        for (int p = 0; p < 5; ++p) f0[p] = *fragp(c, 0, p);
    }
#pragma unroll
    for (int p = 0; p < 5; ++p) f1[p] = *fragp(c, 1, p);
    xqC[0] = *xp(c, 0); xqC[1] = *xp(c, 1);

#pragma unroll
    for (int t5 = 0; t5 < 5; ++t5) {
        const bool valid = (c < cend);
        int cn = c + 8; if (cn > NCHUNKS - 1) cn = NCHUNKS - 1;
        if (valid) {
            // early next-xq issue (double-buffered)
            xqN[0] = *xp(cn, 0); xqN[1] = *xp(cn, 1);

            float cs[2][O_];
            if (MODE == 1) {
                // logits: u = Wt-frag x v ; bd = sum_k u*x
#pragma unroll
                for (int tile = 0; tile < 2; ++tile)
#pragma unroll
                    for (int p = 0; p < 5; ++p) {
                        f16x4 ae, ao;
                        ae[0]=f0[p][0]; ae[1]=f0[p][1]; ae[2]=f0[p][2]; ae[3]=f0[p][3];
                        ao[0]=f0[p][4]; ao[1]=f0[p][5]; ao[2]=f0[p][6]; ao[3]=f0[p][7];
                        const f32x4 ua = __builtin_amdgcn_mfma_f32_16x16x16f16(ae, vf[tile][2*p],   (f32x4)(0.f), 0, 0, 0);
                        const f32x4 ub = __builtin_amdgcn_mfma_f32_16x16x16f16(ao, vf[tile][2*p+1], (f32x4)(0.f), 0, 0, 0);
                        const float4 xq = xqC[tile];
                        float d0 = ua[0] * xq.x; d0 = fmaf(ua[1], xq.y, d0);
                        d0 = fmaf(ua[2], xq.z, d0); d0 = fmaf(ua[3], xq.w, d0);
                        float d1 = ub[0] * xq.x; d1 = fmaf(ub[1], xq.y, d1);
                        d1 = fmaf(ub[2], xq.z, d1); d1 = fmaf(ub[3], xq.w, d1);
                        cs[tile][2*p] = d0; cs[tile][2*p+1] = d1;
                    }
                // f0 consumed -> issue next chunk's Wt frags now (hides L2 latency)
#pragma unroll
                for (int p = 0; p < 5; ++p) f0[p] = *fragp(cn, 0, p);
                // softmax over o per tile (k-halves joined via permlane32_swap)
#pragma unroll
                for (int tile = 0; tile < 2; ++tile) {
                    float ssum = 0.f;
#pragma unroll
                    for (int o = 0; o < O_; ++o) {
                        const unsigned int tt = __float_as_uint(cs[tile][o]);
                        const uint2v sw = __builtin_amdgcn_permlane32_swap(tt, tt, false, false);
                        const float e = __expf(__uint_as_float(sw[0]) + __uint_as_float(sw[1]));
                        cs[tile][o] = e; ssum += e;
                    }
                    const float inv = 1.f / ssum;
#pragma unroll
                    for (int o = 0; o < O_; ++o) cs[tile][o] *= inv;
                }
            }

            // apply: S[d,b] += P-frag x (c*x)
            union F4 { f16x4 v; f16x2 h[2]; };
            F4 xh[2];
            xh[0].v = pack4(xqC[0].x, xqC[0].y, xqC[0].z, xqC[0].w);
            xh[1].v = pack4(xqC[1].x, xqC[1].y, xqC[1].z, xqC[1].w);
#pragma unroll
            for (int p = 0; p < 5; ++p) {
                f16x4 pe, po;
                pe[0]=f1[p][0]; pe[1]=f1[p][1]; pe[2]=f1[p][2]; pe[3]=f1[p][3];
                po[0]=f1[p][4]; po[1]=f1[p][5]; po[2]=f1[p][6]; po[3]=f1[p][7];
#pragma unroll
                for (int tile = 0; tile < 2; ++tile) {
                    F4 ye, yo;
                    if (MODE == 0) { ye = xh[tile]; yo = xh[tile]; }
                    else {
                        const f16x2 ce = splat_h2(cs[tile][2*p]);
                        const f16x2 co = splat_h2(cs[tile][2*p+1]);
                        ye.h[0] = xh[tile].h[0] * ce; ye.h[1] = xh[tile].h[1] * ce;
                        yo.h[0] = xh[tile].h[0] * co; yo.h[1] = xh[tile].h[1] * co;
                    }
                    S[tile][2*p]   = __builtin_amdgcn_mfma_f32_16x16x16f16(pe, ye.v, S[tile][2*p],   0, 0, 0);
                    S[tile][2*p+1] = __builtin_amdgcn_mfma_f32_16x16x16f16(po, yo.v, S[tile][2*p+1], 0, 0, 0);
                }
            }
            // f1/xq consumed -> issue next chunk's loads
#pragma unroll
            for (int p = 0; p < 5; ++p) f1[p] = *fragp(cn, 1, p);
            xqC[0] = xqN[0]; xqC[1] = xqN[1];
        }
        c += 8;
    }

    // ---- inter-wave tree reduction (waves covered disjoint chunks) ----
    auto slot = [&](int w, int tile, int o) {
        return &red[w * 5120 + (tile * O_ + o) * 256 + lane * 4];
    };
#define TREE_WR(WSRC, WDST)                                                 \
    if (wv >= WSRC) {                                                       \
        _Pragma("unroll") for (int tile = 0; tile < 2; ++tile)              \
        _Pragma("unroll") for (int o = 0; o < O_; ++o)                      \
            *(f32x4*)slot(wv - WSRC, tile, o) = S[tile][o];                 \
    }                                                                       \
    __syncthreads();                                                        \
    if (wv < WSRC) {                                                        \
        _Pragma("unroll") for (int tile = 0; tile < 2; ++tile)              \
        _Pragma("unroll") for (int o = 0; o < O_; ++o)                      \
            S[tile][o] += *(f32x4*)slot(wv, tile, o);                       \
    }                                                                       \
    __syncthreads();

    TREE_WR(4, )
    TREE_WR(2, )
    TREE_WR(1, )
#undef TREE_WR

    if (wv == 0) {
#pragma unroll
        for (int tile = 0; tile < 2; ++tile)
#pragma unroll
            for (int o = 0; o < O_; ++o) {
                float* pp = parts + (long)ib * PSET
                          + ((long)(b0 + tile * 16) * O_ + o) * D_ + g * 4;
                *(f32x4*)pp = S[tile][o];
            }
    }
}

// ---------------------------------------------------------------------------
// Reduce 64 partial sets -> s[b,o,d]; squash over d; update v_buf / out.
// Grid 1280 (one block per (b,o)).
// ---------------------------------------------------------------------------
__global__ __launch_bounds__(256)
void reduce_squash(const float* __restrict__ parts, float* __restrict__ v_buf,
                   float* __restrict__ out, float kscale, float pre, int mode)
{
    __shared__ float red2[4][16];
    const int tid  = threadIdx.x;
    const int lane = tid & 63;
    const int wv   = tid >> 6;
    const int g2   = blockIdx.x;        // (b*O + o)
    const int pg   = tid >> 4;          // 0..15
    const int d    = tid & 15;

    float s = 0.f;
#pragma unroll
    for (int k = 0; k < 4; ++k)
        s += parts[(long)(pg * 4 + k) * PSET + g2 * D_ + d];

    s += __shfl_xor(s, 16);
    s += __shfl_xor(s, 32);
    if (lane < 16) red2[wv][lane] = s;
    __syncthreads();

    if (tid < 16) {
        float tot = (red2[0][tid] + red2[1][tid]) + (red2[2][tid] + red2[3][tid]);
        tot *= pre;
        float n2 = tot * tot;
        n2 += __shfl_xor(n2, 1);
        n2 += __shfl_xor(n2, 2);
        n2 += __shfl_xor(n2, 4);
        n2 += __shfl_xor(n2, 8);
        const float n     = sqrtf(n2);
        const float scale = n2 / ((1.f + n2) * (n + 1e-8f));
        const float o_    = scale * tot;
        const int idx = g2 * D_ + tid;
        if (mode == 0)      { v_buf[idx] = o_;  out[idx]  = kscale * o_; }
        else if (mode == 1) { v_buf[idx] += o_; out[idx] += kscale * o_; }
        else                {                   out[idx] += kscale * o_; }
    }
}

// ---------------------------------------------------------------------------
extern "C" void kernel_launch(void* const* d_in, const int* in_sizes, int n_in,
                              void* d_out, int out_size, void* d_ws, size_t ws_size,
                              hipStream_t stream)
{
    const float* x = (const float*)d_in[0];   // [128,4608,8]
    const float* w = (const float*)d_in[1];   // [10,4608,16,8]
    float* out   = (float*)d_out;             // [128,10,16]
    float* parts = (float*)d_ws;                          // 64*80KB = 5.24 MB
    float* v_buf = parts + (long)NIB * PSET;              // 80 KB
    _Float16* pw = (_Float16*)(v_buf + B_ * O_ * D_);     // 23.6 MB frag images

    prep_kernel<<<NCHUNKS, 256, 0, stream>>>(w, pw);

    // iter 0: c = 1/10 uniform (folded via pre=0.1)
    pass_kernel<0><<<256, 512, 0, stream>>>(x, pw, v_buf, parts);
    reduce_squash<<<1280, 256, 0, stream>>>(parts, v_buf, out, 0.3f, 0.1f, 0);

    // iter 1: b1 = <out0, xh>
    pass_kernel<1><<<256, 512, 0, stream>>>(x, pw, v_buf, parts);
    reduce_squash<<<1280, 256, 0, stream>>>(parts, v_buf, out, 0.3f, 1.0f, 1);

    // iter 2: b2 = <out0 + out1, xh>
    pass_kernel<1><<<256, 512, 0, stream>>>(x, pw, v_buf, parts);
    reduce_squash<<<1280, 256, 0, stream>>>(parts, v_buf, out, 0.4f, 1.0f, 2);
}